// Round 1
// baseline (5744.326 us; speedup 1.0000x reference)
//
#include <hip/hip_runtime.h>
#include <hip/hip_bf16.h>
#include <math.h>

// Sliding-window attention module, fp32 correctness-first baseline.
// Stage 1: QKV GEMM with scatter epilogue -> q,k,v in [B,H,S,d]
// Stage 2: banded flash attention (window=512) -> attn in [B,S,E]
// Stage 3: out-projection GEMM -> d_out
//
// ws layout (floats): q[16.7M] k[16.7M] v[16.7M] attn[16.7M] = 268 MB total.

#define SEQ   4096
#define BATCH 2
#define EMBED 2048
#define HEADS 16
#define HDIM  128
#define NELEM (BATCH * HEADS * SEQ * HDIM)  // 16777216 floats per buffer

// ---------------------------------------------------------------------------
// C[M,N] = A[M,K] * B[N,K]^T   (A, B row-major with K innermost; "NT" GEMM)
// SCATTER=1: instead of C, scatter each 128-col tile (== one head slice of
// q/k/v) into [B,H,S,d]-layout buffers.
// ---------------------------------------------------------------------------
template <int SCATTER>
__global__ void gemm_nt_kernel(const float* __restrict__ A,
                               const float* __restrict__ B,
                               float* __restrict__ C,
                               float* __restrict__ Qo,
                               float* __restrict__ Ko,
                               float* __restrict__ Vo,
                               int M, int N, int K)
{
    // pad 34: row*34 even -> float2 (8B) aligned reads; banks conflict-free:
    // a-rows {ty+16i} -> 4 distinct bank-pairs (x16 broadcast),
    // b-rows {tx+16j} -> 16 distinct even bank-pairs.
    __shared__ float As[128][34];
    __shared__ float Bs[128][34];

    const int tid = threadIdx.x;
    const int tx  = tid & 15;
    const int ty  = tid >> 4;
    const int m0  = blockIdx.y * 128;
    const int n0  = blockIdx.x * 128;

    float acc[8][8];
#pragma unroll
    for (int i = 0; i < 8; ++i)
#pragma unroll
        for (int j = 0; j < 8; ++j) acc[i][j] = 0.f;

    for (int k0 = 0; k0 < K; k0 += 32) {
#pragma unroll
        for (int u = 0; u < 4; ++u) {
            const int f4  = tid + u * 256;        // 0..1023 float4 slots
            const int row = f4 >> 3;
            const int c4  = (f4 & 7) * 4;
            const float4 va = *(const float4*)(A + (size_t)(m0 + row) * K + k0 + c4);
            As[row][c4 + 0] = va.x; As[row][c4 + 1] = va.y;
            As[row][c4 + 2] = va.z; As[row][c4 + 3] = va.w;
            const float4 vb = *(const float4*)(B + (size_t)(n0 + row) * K + k0 + c4);
            Bs[row][c4 + 0] = vb.x; Bs[row][c4 + 1] = vb.y;
            Bs[row][c4 + 2] = vb.z; Bs[row][c4 + 3] = vb.w;
        }
        __syncthreads();

#pragma unroll
        for (int kk = 0; kk < 32; kk += 2) {
            float a0[8], a1[8], b0[8], b1[8];
#pragma unroll
            for (int i = 0; i < 8; ++i) {
                const float2 ra = *(const float2*)&As[ty + 16 * i][kk];
                a0[i] = ra.x; a1[i] = ra.y;
            }
#pragma unroll
            for (int j = 0; j < 8; ++j) {
                const float2 rb = *(const float2*)&Bs[tx + 16 * j][kk];
                b0[j] = rb.x; b1[j] = rb.y;
            }
#pragma unroll
            for (int i = 0; i < 8; ++i)
#pragma unroll
                for (int j = 0; j < 8; ++j) {
                    acc[i][j] = fmaf(a0[i], b0[j], acc[i][j]);
                    acc[i][j] = fmaf(a1[i], b1[j], acc[i][j]);
                }
        }
        __syncthreads();
    }

    if (SCATTER) {
        // n0 covers exactly one head-slice: t = q/k/v selector, h = head.
        const int t = blockIdx.x >> 4;
        const int h = blockIdx.x & 15;
        float* dst = (t == 0) ? Qo : (t == 1) ? Ko : Vo;
#pragma unroll
        for (int i = 0; i < 8; ++i) {
            const int m = m0 + ty + 16 * i;
            const int b = m >> 12;     // / SEQ
            const int s = m & 4095;    // % SEQ
            float* drow = dst + ((size_t)(b * HEADS + h) * SEQ + s) * HDIM;
#pragma unroll
            for (int j = 0; j < 8; ++j) drow[tx + 16 * j] = acc[i][j];
        }
    } else {
#pragma unroll
        for (int i = 0; i < 8; ++i) {
            const int m = m0 + ty + 16 * i;
            float* crow = C + (size_t)m * N + n0;
#pragma unroll
            for (int j = 0; j < 8; ++j) crow[tx + 16 * j] = acc[i][j];
        }
    }
}

// ---------------------------------------------------------------------------
// Sliding-window causal attention, window = 512 (key j valid iff
// 0 <= gq - gk <= 512 and gk >= 0).  One block per (b, h, 64-query tile).
// Wave w owns queries w*16..w*16+15; 4 lanes per query, 32 dims per lane.
// Rotation swizzle: lane `part` accesses dim part*32 + ((t + part*8) & 31)
// so the 4 broadcast LDS addresses per read hit disjoint banks.
// ---------------------------------------------------------------------------
__global__ void swa_kernel(const float* __restrict__ Qb,
                           const float* __restrict__ Kb,
                           const float* __restrict__ Vb,
                           float* __restrict__ O /* [B,S,E] */)
{
    __shared__ float Ks[64][128];
    __shared__ float Vs[64][128];

    const int bid  = blockIdx.x;
    const int qt   = bid & 63;
    const int h    = (bid >> 6) & 15;
    const int b    = bid >> 10;
    const int q0   = qt * 64;
    const int tid  = threadIdx.x;
    const int wave = tid >> 6;
    const int lane = tid & 63;
    const int qi   = wave * 16 + (lane >> 2);
    const int part = lane & 3;
    const int gq   = q0 + qi;
    const size_t hb = (size_t)(b * HEADS + h) * SEQ * HDIM;

    float qreg[32];
    const float* qrow = Qb + hb + (size_t)gq * HDIM;
#pragma unroll
    for (int t = 0; t < 32; ++t)
        qreg[t] = qrow[part * 32 + ((t + part * 8) & 31)] * 0.088388347648318447f;

    float o[32];
#pragma unroll
    for (int t = 0; t < 32; ++t) o[t] = 0.f;
    float m = -INFINITY, l = 0.f;

    for (int kt = 0; kt < 9; ++kt) {
        const int gk0 = q0 - 512 + kt * 64;
        if (gk0 + 64 <= 0) continue;  // block-uniform: whole tile below key 0

        // stage K,V tile (clamp rows below 0; they are masked out anyway)
#pragma unroll
        for (int u = 0; u < 8; ++u) {
            const int f4  = tid + u * 256;      // 0..2047 float4 slots
            const int row = f4 >> 5;
            const int c   = (f4 & 31) * 4;
            const int gk  = gk0 + row;
            const size_t src = hb + (size_t)(gk < 0 ? 0 : gk) * HDIM + c;
            *(float4*)&Ks[row][c] = *(const float4*)(Kb + src);
            *(float4*)&Vs[row][c] = *(const float4*)(Vb + src);
        }
        __syncthreads();

        int kmax = gq - gk0;            // gk <= gq
        if (kmax > 63) kmax = 63;
        int klo = (kt == 0) ? qi : 0;   // gk >= gq-512 only binds at kt==0
        if (gk0 < 0 && klo < -gk0) klo = -gk0;

        for (int kk = klo; kk <= kmax; ++kk) {
            float s = 0.f;
#pragma unroll
            for (int t4 = 0; t4 < 8; ++t4) {
                const float4 k4 =
                    *(const float4*)&Ks[kk][part * 32 + ((t4 * 4 + part * 8) & 31)];
                s = fmaf(qreg[t4 * 4 + 0], k4.x, s);
                s = fmaf(qreg[t4 * 4 + 1], k4.y, s);
                s = fmaf(qreg[t4 * 4 + 2], k4.z, s);
                s = fmaf(qreg[t4 * 4 + 3], k4.w, s);
            }
            s += __shfl_xor(s, 1);
            s += __shfl_xor(s, 2);

            if (s > m) {                 // rare (~ln(577) times per query)
                const float corr = __expf(m - s);
#pragma unroll
                for (int t = 0; t < 32; ++t) o[t] *= corr;
                l *= corr;
                m = s;
            }
            const float p = __expf(s - m);
            l += p;
#pragma unroll
            for (int t4 = 0; t4 < 8; ++t4) {
                const float4 v4 =
                    *(const float4*)&Vs[kk][part * 32 + ((t4 * 4 + part * 8) & 31)];
                o[t4 * 4 + 0] = fmaf(p, v4.x, o[t4 * 4 + 0]);
                o[t4 * 4 + 1] = fmaf(p, v4.y, o[t4 * 4 + 1]);
                o[t4 * 4 + 2] = fmaf(p, v4.z, o[t4 * 4 + 2]);
                o[t4 * 4 + 3] = fmaf(p, v4.w, o[t4 * 4 + 3]);
            }
        }
        __syncthreads();
    }

    const float inv = 1.f / l;
    float* orow = O + ((size_t)(b * SEQ + gq)) * EMBED + h * HDIM;
#pragma unroll
    for (int t = 0; t < 32; ++t)
        orow[part * 32 + ((t + part * 8) & 31)] = o[t] * inv;
}

// ---------------------------------------------------------------------------
extern "C" void kernel_launch(void* const* d_in, const int* in_sizes, int n_in,
                              void* d_out, int out_size, void* d_ws, size_t ws_size,
                              hipStream_t stream)
{
    const float* x     = (const float*)d_in[0];
    const float* w_qkv = (const float*)d_in[1];
    const float* w_out = (const float*)d_in[2];
    float* out  = (float*)d_out;

    float* q    = (float*)d_ws;
    float* k    = q + NELEM;
    float* v    = k + NELEM;
    float* attn = v + NELEM;

    const int M = BATCH * SEQ;  // 8192
    dim3 blk(256);

    dim3 g_qkv(3 * EMBED / 128, M / 128);  // 48 x 64
    hipLaunchKernelGGL((gemm_nt_kernel<1>), g_qkv, blk, 0, stream,
                       x, w_qkv, (float*)nullptr, q, k, v, M, 3 * EMBED, EMBED);

    dim3 g_attn(BATCH * HEADS * (SEQ / 64));  // 2048
    hipLaunchKernelGGL(swa_kernel, g_attn, blk, 0, stream, q, k, v, attn);

    dim3 g_out(EMBED / 128, M / 128);  // 16 x 64
    hipLaunchKernelGGL((gemm_nt_kernel<0>), g_out, blk, 0, stream,
                       attn, w_out, out, (float*)nullptr, (float*)nullptr,
                       (float*)nullptr, M, EMBED, EMBED);
}

// Round 2
// 1780.066 us; speedup vs baseline: 3.2270x; 3.2270x over previous
//
#include <hip/hip_runtime.h>
#include <hip/hip_bf16.h>
#include <math.h>

// Stage 0: cast x, w_qkv, w_out -> bf16
// Stage 1: bf16 MFMA QKV GEMM, scatter epilogue -> q,k,v fp32 [B,H,S,d]
// Stage 2: fp32 banded flash attention (window=512) -> attn bf16 [B,S,E]
// Stage 3: bf16 MFMA out-proj GEMM -> d_out fp32
//
// ws layout (bytes), total exactly 268435456 (= footprint proven in R1):
//   q   f32 [16.7M]  @ 0
//   k   f32 [16.7M]  @ 67108864
//   v   f32 [16.7M]  @ 134217728
//   xb  bf16[16.7M]  @ 201326592   (aliased: attn bf16 after QKV GEMM consumes xb)
//   wqkvb bf16[12.6M]@ 234881024
//   woutb bf16[4.2M] @ 260046848

#define SEQ   4096
#define BATCH 2
#define EMBED 2048
#define HEADS 16
#define HDIM  128
#define NELEM (BATCH * SEQ * EMBED)  // 16777216

typedef __attribute__((ext_vector_type(8))) short short8;
typedef __attribute__((ext_vector_type(4))) float f32x4;

__device__ __forceinline__ unsigned short f2bf(float f) {
    unsigned int u = __float_as_uint(f);
    u = (u + 0x7fff + ((u >> 16) & 1)) >> 16;  // round-to-nearest-even
    return (unsigned short)u;
}

// ---------------------------------------------------------------------------
// fp32 -> bf16 cast, 8 elems/thread
// ---------------------------------------------------------------------------
__global__ void cast_bf16_kernel(const float* __restrict__ src,
                                 unsigned short* __restrict__ dst, int n8)
{
    const int i = blockIdx.x * blockDim.x + threadIdx.x;
    if (i >= n8) return;
    const float4 v0 = ((const float4*)src)[2 * i];
    const float4 v1 = ((const float4*)src)[2 * i + 1];
    union { unsigned short us[8]; uint4 u4; } o;
    o.us[0] = f2bf(v0.x); o.us[1] = f2bf(v0.y); o.us[2] = f2bf(v0.z); o.us[3] = f2bf(v0.w);
    o.us[4] = f2bf(v1.x); o.us[5] = f2bf(v1.y); o.us[6] = f2bf(v1.z); o.us[7] = f2bf(v1.w);
    ((uint4*)dst)[i] = o.u4;
}

// ---------------------------------------------------------------------------
// bf16 NT-GEMM: C[M,N] = A[M,K] * B[N,K]^T, fp32 accum/output.
// 128x128 tile, BK=64, 4 waves (2x2), 64x64 per wave, mfma_f32_16x16x32_bf16.
// LDS linear (global_load_lds), XOR swizzle byte^=((row&7)<<4) applied via
// pre-swizzled GLOBAL source + swizzled ds_read (both-sides rule).
// SCATTER=1: each 128-col tile = one head slice; scatter to q/k/v fp32.
// ---------------------------------------------------------------------------
template <int SCATTER>
__global__ __launch_bounds__(256)
void gemm_bf16_kernel(const unsigned short* __restrict__ A,
                      const unsigned short* __restrict__ B,
                      float* __restrict__ C,
                      float* __restrict__ Qo, float* __restrict__ Ko,
                      float* __restrict__ Vo,
                      int M, int N, int K)
{
    __shared__ __align__(16) char lds[32768];  // sA 16KB | sB 16KB
    char* sA = lds;
    char* sB = lds + 16384;

    const int tid  = threadIdx.x;
    const int lane = tid & 63;
    const int w    = tid >> 6;       // wave 0..3
    const int wr   = w >> 1;         // wave row 0..1 (64 rows each)
    const int wc   = w & 1;          // wave col 0..1
    const int l16  = lane & 15;
    const int kg   = lane >> 4;      // k-group 0..3
    const int m0   = blockIdx.y * 128;
    const int n0   = blockIdx.x * 128;

    // staging geometry: per instr u, rows u*32 + w*8 + (lane>>3), 8 chunks/row.
    const int srow   = w * 8 + (lane >> 3);
    const int schunk = (lane & 7) ^ (lane >> 3);  // inverse-swizzle on source

    f32x4 acc[4][4];
#pragma unroll
    for (int i = 0; i < 4; ++i)
#pragma unroll
        for (int j = 0; j < 4; ++j) acc[i][j] = (f32x4)0.f;

    for (int k0 = 0; k0 < K; k0 += 64) {
#pragma unroll
        for (int u = 0; u < 4; ++u) {
            const char* ga = (const char*)(A + (size_t)(m0 + u * 32 + srow) * K + k0 + schunk * 8);
            unsigned int la = __builtin_amdgcn_readfirstlane(
                (unsigned int)(uintptr_t)(sA + u * 4096 + w * 1024));
            asm volatile("s_mov_b32 m0, %0\n\t"
                         "global_load_lds_dwordx4 %1, off"
                         :: "s"(la), "v"(ga) : "memory");
            const char* gb = (const char*)(B + (size_t)(n0 + u * 32 + srow) * K + k0 + schunk * 8);
            unsigned int lb = __builtin_amdgcn_readfirstlane(
                (unsigned int)(uintptr_t)(sB + u * 4096 + w * 1024));
            asm volatile("s_mov_b32 m0, %0\n\t"
                         "global_load_lds_dwordx4 %1, off"
                         :: "s"(lb), "v"(gb) : "memory");
        }
        asm volatile("s_waitcnt vmcnt(0)" ::: "memory");  // asm loads are untracked
        __syncthreads();

#pragma unroll
        for (int kk = 0; kk < 2; ++kk) {
            const int co = ((kk * 4 + kg) ^ (l16 & 7)) * 16;  // swizzled chunk byte
            short8 af[4], bf[4];
#pragma unroll
            for (int i = 0; i < 4; ++i)
                af[i] = *(const short8*)(sA + (wr * 64 + i * 16 + l16) * 128 + co);
#pragma unroll
            for (int j = 0; j < 4; ++j)
                bf[j] = *(const short8*)(sB + (wc * 64 + j * 16 + l16) * 128 + co);
#pragma unroll
            for (int i = 0; i < 4; ++i)
#pragma unroll
                for (int j = 0; j < 4; ++j)
                    acc[i][j] = __builtin_amdgcn_mfma_f32_16x16x32_bf16(
                        af[i], bf[j], acc[i][j], 0, 0, 0);
        }
        __syncthreads();
    }

    if (SCATTER) {
        const int t = blockIdx.x >> 4;   // qkv selector
        const int h = blockIdx.x & 15;   // head
        float* dst = (t == 0) ? Qo : (t == 1) ? Ko : Vo;
#pragma unroll
        for (int i = 0; i < 4; ++i)
#pragma unroll
            for (int r = 0; r < 4; ++r) {
                const int m = m0 + wr * 64 + i * 16 + kg * 4 + r;
                const int b = m >> 12, s = m & 4095;
                float* drow = dst + ((size_t)((b << 4) + h) * SEQ + s) * HDIM
                              + wc * 64 + l16;
#pragma unroll
                for (int j = 0; j < 4; ++j) drow[j * 16] = acc[i][j][r];
            }
    } else {
#pragma unroll
        for (int i = 0; i < 4; ++i)
#pragma unroll
            for (int r = 0; r < 4; ++r) {
                const int m = m0 + wr * 64 + i * 16 + kg * 4 + r;
                float* crow = C + (size_t)m * N + n0 + wc * 64 + l16;
#pragma unroll
                for (int j = 0; j < 4; ++j) crow[j * 16] = acc[i][j][r];
            }
    }
}

// ---------------------------------------------------------------------------
// Sliding-window causal attention (validated in R1), fp32 math, bf16 output.
// One block per (b, h, 64-query tile); wave w owns 16 queries, 4 lanes/query.
// ---------------------------------------------------------------------------
__global__ void swa_kernel(const float* __restrict__ Qb,
                           const float* __restrict__ Kb,
                           const float* __restrict__ Vb,
                           unsigned short* __restrict__ O /* bf16 [B,S,E] */)
{
    __shared__ float Ks[64][128];
    __shared__ float Vs[64][128];

    const int bid  = blockIdx.x;
    const int qt   = bid & 63;
    const int h    = (bid >> 6) & 15;
    const int b    = bid >> 10;
    const int q0   = qt * 64;
    const int tid  = threadIdx.x;
    const int wave = tid >> 6;
    const int lane = tid & 63;
    const int qi   = wave * 16 + (lane >> 2);
    const int part = lane & 3;
    const int gq   = q0 + qi;
    const size_t hb = (size_t)(b * HEADS + h) * SEQ * HDIM;

    float qreg[32];
    const float* qrow = Qb + hb + (size_t)gq * HDIM;
#pragma unroll
    for (int t = 0; t < 32; ++t)
        qreg[t] = qrow[part * 32 + ((t + part * 8) & 31)] * 0.088388347648318447f;

    float o[32];
#pragma unroll
    for (int t = 0; t < 32; ++t) o[t] = 0.f;
    float m = -INFINITY, l = 0.f;

    for (int kt = 0; kt < 9; ++kt) {
        const int gk0 = q0 - 512 + kt * 64;
        if (gk0 + 64 <= 0) continue;

#pragma unroll
        for (int u = 0; u < 8; ++u) {
            const int f4  = tid + u * 256;
            const int row = f4 >> 5;
            const int c   = (f4 & 31) * 4;
            const int gk  = gk0 + row;
            const size_t src = hb + (size_t)(gk < 0 ? 0 : gk) * HDIM + c;
            *(float4*)&Ks[row][c] = *(const float4*)(Kb + src);
            *(float4*)&Vs[row][c] = *(const float4*)(Vb + src);
        }
        __syncthreads();

        int kmax = gq - gk0;
        if (kmax > 63) kmax = 63;
        int klo = (kt == 0) ? qi : 0;
        if (gk0 < 0 && klo < -gk0) klo = -gk0;

        for (int kk = klo; kk <= kmax; ++kk) {
            float s = 0.f;
#pragma unroll
            for (int t4 = 0; t4 < 8; ++t4) {
                const float4 k4 =
                    *(const float4*)&Ks[kk][part * 32 + ((t4 * 4 + part * 8) & 31)];
                s = fmaf(qreg[t4 * 4 + 0], k4.x, s);
                s = fmaf(qreg[t4 * 4 + 1], k4.y, s);
                s = fmaf(qreg[t4 * 4 + 2], k4.z, s);
                s = fmaf(qreg[t4 * 4 + 3], k4.w, s);
            }
            s += __shfl_xor(s, 1);
            s += __shfl_xor(s, 2);

            if (s > m) {
                const float corr = __expf(m - s);
#pragma unroll
                for (int t = 0; t < 32; ++t) o[t] *= corr;
                l *= corr;
                m = s;
            }
            const float p = __expf(s - m);
            l += p;
#pragma unroll
            for (int t4 = 0; t4 < 8; ++t4) {
                const float4 v4 =
                    *(const float4*)&Vs[kk][part * 32 + ((t4 * 4 + part * 8) & 31)];
                o[t4 * 4 + 0] = fmaf(p, v4.x, o[t4 * 4 + 0]);
                o[t4 * 4 + 1] = fmaf(p, v4.y, o[t4 * 4 + 1]);
                o[t4 * 4 + 2] = fmaf(p, v4.z, o[t4 * 4 + 2]);
                o[t4 * 4 + 3] = fmaf(p, v4.w, o[t4 * 4 + 3]);
            }
        }
        __syncthreads();
    }

    const float inv = 1.f / l;
    unsigned short* orow = O + ((size_t)(b * SEQ + gq)) * EMBED + h * HDIM;
#pragma unroll
    for (int t = 0; t < 32; ++t)
        orow[part * 32 + ((t + part * 8) & 31)] = f2bf(o[t] * inv);
}

// ---------------------------------------------------------------------------
extern "C" void kernel_launch(void* const* d_in, const int* in_sizes, int n_in,
                              void* d_out, int out_size, void* d_ws, size_t ws_size,
                              hipStream_t stream)
{
    const float* x     = (const float*)d_in[0];
    const float* w_qkv = (const float*)d_in[1];
    const float* w_out = (const float*)d_in[2];
    float* out = (float*)d_out;

    char* ws = (char*)d_ws;
    float* q            = (float*)(ws);
    float* k            = (float*)(ws + 67108864);
    float* v            = (float*)(ws + 134217728);
    unsigned short* xb  = (unsigned short*)(ws + 201326592);  // aliased w/ attnb
    unsigned short* attnb = xb;
    unsigned short* wqkvb = (unsigned short*)(ws + 234881024);
    unsigned short* woutb = (unsigned short*)(ws + 260046848);

    const int M = BATCH * SEQ;  // 8192
    dim3 blk(256);

    // casts
    hipLaunchKernelGGL(cast_bf16_kernel, dim3(NELEM / 8 / 256), blk, 0, stream,
                       x, xb, NELEM / 8);
    hipLaunchKernelGGL(cast_bf16_kernel, dim3(3 * EMBED * EMBED / 8 / 256), blk, 0, stream,
                       w_qkv, wqkvb, 3 * EMBED * EMBED / 8);
    hipLaunchKernelGGL(cast_bf16_kernel, dim3(EMBED * EMBED / 8 / 256), blk, 0, stream,
                       w_out, woutb, EMBED * EMBED / 8);

    // QKV GEMM (scatter)
    hipLaunchKernelGGL((gemm_bf16_kernel<1>), dim3(3 * EMBED / 128, M / 128), blk, 0, stream,
                       xb, wqkvb, (float*)nullptr, q, k, v, M, 3 * EMBED, EMBED);

    // attention
    hipLaunchKernelGGL(swa_kernel, dim3(BATCH * HEADS * (SEQ / 64)), blk, 0, stream,
                       q, k, v, attnb);

    // out projection
    hipLaunchKernelGGL((gemm_bf16_kernel<0>), dim3(EMBED / 128, M / 128), blk, 0, stream,
                       attnb, woutb, out, (float*)nullptr, (float*)nullptr,
                       (float*)nullptr, M, EMBED, EMBED);
}

// Round 4
// 456.297 us; speedup vs baseline: 12.5890x; 3.9011x over previous
//
#include <hip/hip_runtime.h>
#include <hip/hip_bf16.h>
#include <math.h>

// Stage 0: cast x, w_qkv, w_out -> bf16
// Stage 1a: bf16 MFMA GEMM (x * Wqk^T), scatter -> q,k bf16 [B,H,S,128]
// Stage 1b: bf16 MFMA GEMM (Wv * x^T), scatter -> vt bf16 [B,H,128,S] with
//           sigma key-permutation baked in (see below)
// Stage 2: MFMA flash attention (window=512) -> attn bf16 [B,S,E]
// Stage 3: bf16 MFMA out-proj GEMM -> d_out fp32
//
// sigma: within each 64-key tile, contraction slot c = (w:1,g:2,t:1,r:2) holds
// key (w:1,t:1,g:2,r:2). This makes each lane's PV A-fragment consist purely
// of its OWN QK^T outputs (zero cross-lane traffic for P).

#define SEQ   4096
#define BATCH 2
#define EMBED 2048
#define HEADS 16
#define HDIM  128
#define NELEM (BATCH * SEQ * EMBED)  // 16777216
#define SCL2E (0.088388347648318447f * 1.4426950408889634f)  // 1/sqrt(128)*log2(e)

typedef __attribute__((ext_vector_type(8))) short short8;
typedef __attribute__((ext_vector_type(4))) float f32x4;

__device__ __forceinline__ unsigned short f2bf(float f) {
    unsigned int u = __float_as_uint(f);
    u = (u + 0x7fff + ((u >> 16) & 1)) >> 16;  // round-to-nearest-even
    return (unsigned short)u;
}

__device__ __forceinline__ unsigned int cvt_pk_bf16(float a, float b) {
    unsigned int r;
    asm volatile("v_cvt_pk_bf16_f32 %0, %1, %2" : "=v"(r) : "v"(a), "v"(b));
    return r;
}

// ---------------------------------------------------------------------------
__global__ void cast_bf16_kernel(const float* __restrict__ src,
                                 unsigned short* __restrict__ dst, int n8)
{
    const int i = blockIdx.x * blockDim.x + threadIdx.x;
    if (i >= n8) return;
    const float4 v0 = ((const float4*)src)[2 * i];
    const float4 v1 = ((const float4*)src)[2 * i + 1];
    union { unsigned short us[8]; uint4 u4; } o;
    o.us[0] = f2bf(v0.x); o.us[1] = f2bf(v0.y); o.us[2] = f2bf(v0.z); o.us[3] = f2bf(v0.w);
    o.us[4] = f2bf(v1.x); o.us[5] = f2bf(v1.y); o.us[6] = f2bf(v1.z); o.us[7] = f2bf(v1.w);
    ((uint4*)dst)[i] = o.u4;
}

// ---------------------------------------------------------------------------
// bf16 NT-GEMM, 128x128 tile, BK=64, 4 waves, mfma_f32_16x16x32_bf16.
// MODE 0: C fp32 row-major [M,N]
// MODE 1: scatter bf16 -> P0=q, P1=k at [B,H,S,128] (N=4096 = {q,k}x16 heads)
// MODE 2: scatter bf16 -> P0=vt at [B,H,128,S], sigma-permuted within 64-col tiles
// ---------------------------------------------------------------------------
template <int MODE>
__global__ __launch_bounds__(256)
void gemm_bf16_kernel(const unsigned short* __restrict__ A,
                      const unsigned short* __restrict__ B,
                      float* __restrict__ C,
                      unsigned short* __restrict__ P0,
                      unsigned short* __restrict__ P1,
                      int M, int N, int K)
{
    __shared__ __align__(16) char lds[32768];  // sA 16KB | sB 16KB
    char* sA = lds;
    char* sB = lds + 16384;

    const int tid  = threadIdx.x;
    const int lane = tid & 63;
    const int w    = tid >> 6;
    const int wr   = w >> 1;
    const int wc   = w & 1;
    const int l16  = lane & 15;
    const int kg   = lane >> 4;
    const int m0   = blockIdx.y * 128;
    const int n0   = blockIdx.x * 128;

    const int srow   = w * 8 + (lane >> 3);
    const int schunk = (lane & 7) ^ (lane >> 3);

    f32x4 acc[4][4];
#pragma unroll
    for (int i = 0; i < 4; ++i)
#pragma unroll
        for (int j = 0; j < 4; ++j) acc[i][j] = (f32x4)0.f;

    for (int k0 = 0; k0 < K; k0 += 64) {
#pragma unroll
        for (int u = 0; u < 4; ++u) {
            const char* ga = (const char*)(A + (size_t)(m0 + u * 32 + srow) * K + k0 + schunk * 8);
            unsigned int la = __builtin_amdgcn_readfirstlane(
                (unsigned int)(uintptr_t)(sA + u * 4096 + w * 1024));
            asm volatile("s_mov_b32 m0, %0\n\t"
                         "global_load_lds_dwordx4 %1, off"
                         :: "s"(la), "v"(ga) : "memory");
            const char* gb = (const char*)(B + (size_t)(n0 + u * 32 + srow) * K + k0 + schunk * 8);
            unsigned int lb = __builtin_amdgcn_readfirstlane(
                (unsigned int)(uintptr_t)(sB + u * 4096 + w * 1024));
            asm volatile("s_mov_b32 m0, %0\n\t"
                         "global_load_lds_dwordx4 %1, off"
                         :: "s"(lb), "v"(gb) : "memory");
        }
        asm volatile("s_waitcnt vmcnt(0)" ::: "memory");
        __syncthreads();

#pragma unroll
        for (int kk = 0; kk < 2; ++kk) {
            const int co = ((kk * 4 + kg) ^ (l16 & 7)) * 16;
            short8 af[4], bf[4];
#pragma unroll
            for (int i = 0; i < 4; ++i)
                af[i] = *(const short8*)(sA + (wr * 64 + i * 16 + l16) * 128 + co);
#pragma unroll
            for (int j = 0; j < 4; ++j)
                bf[j] = *(const short8*)(sB + (wc * 64 + j * 16 + l16) * 128 + co);
#pragma unroll
            for (int i = 0; i < 4; ++i)
#pragma unroll
                for (int j = 0; j < 4; ++j)
                    acc[i][j] = __builtin_amdgcn_mfma_f32_16x16x32_bf16(
                        af[i], bf[j], acc[i][j], 0, 0, 0);
        }
        __syncthreads();
    }

    if (MODE == 1) {
        const int t = blockIdx.x >> 4;
        const int h = blockIdx.x & 15;
        unsigned short* dst = t ? P1 : P0;
#pragma unroll
        for (int i = 0; i < 4; ++i)
#pragma unroll
            for (int r = 0; r < 4; ++r) {
                const int m = m0 + wr * 64 + i * 16 + kg * 4 + r;
                const int b = m >> 12, s = m & 4095;
                unsigned short* drow = dst + ((size_t)((b << 4) + h) * SEQ + s) * HDIM
                                       + wc * 64 + l16;
#pragma unroll
                for (int j = 0; j < 4; ++j) drow[j * 16] = f2bf(acc[i][j][r]);
            }
    } else if (MODE == 2) {
        // rows m = v-row (h,d); cols n = (b,s); write vt[b,h][d][sigma'd s]
#pragma unroll
        for (int i = 0; i < 4; ++i)
#pragma unroll
            for (int r = 0; r < 4; ++r) {
                const int m = m0 + wr * 64 + i * 16 + kg * 4 + r;
                const int h = m >> 7, d = m & 127;
#pragma unroll
                for (int j = 0; j < 4; ++j) {
                    const int n = n0 + wc * 64 + j * 16 + l16;
                    const int b = n >> 12, s = n & 4095;
                    const int sl = s & 63;
                    const int c = (sl & 0x23) | ((sl & 0x0C) << 1) | ((sl & 0x10) >> 2);
                    P0[((size_t)((b << 4) + h) * HDIM + d) * SEQ + (s & ~63) + c] =
                        f2bf(acc[i][j][r]);
                }
            }
    } else {
#pragma unroll
        for (int i = 0; i < 4; ++i)
#pragma unroll
            for (int r = 0; r < 4; ++r) {
                const int m = m0 + wr * 64 + i * 16 + kg * 4 + r;
                float* crow = C + (size_t)m * N + n0 + wc * 64 + l16;
#pragma unroll
                for (int j = 0; j < 4; ++j) crow[j * 16] = acc[i][j][r];
            }
    }
}

// ---------------------------------------------------------------------------
// MFMA flash attention. Block = 512 threads = 8 waves; 128 queries per block
// (wave w owns queries q0+16w..+15). 10 KV tiles of 64 keys.
// K tile [64 keys][128 d] bf16 @ lds+0; Vt tile [128 d][64 keys(sigma)] @ +16384.
// Swapped QK^T: A=K-frag(rows=keys), B=Q-frag(rows=queries) -> lane holds
// scores s[kb][r] for query l16, key 16*kb+4*kg+r. PV: A=P (rows=queries,
// built locally thanks to sigma), B=Vt (rows=d) -> O rows q=4*kg+r, cols d.
// ---------------------------------------------------------------------------
__global__ __launch_bounds__(512)
void swa_mfma_kernel(const unsigned short* __restrict__ Qg,
                     const unsigned short* __restrict__ Kg,
                     const unsigned short* __restrict__ Vtg,
                     unsigned short* __restrict__ O /* bf16 [B,S,E] */)
{
    __shared__ __align__(16) char lds[32768];

    const int bid = blockIdx.x;
    const int qt  = bid & 31;
    const int h   = (bid >> 5) & 15;
    const int b   = bid >> 9;
    const int q0  = qt * 128;
    const int tid  = threadIdx.x;
    const int w    = tid >> 6;
    const int lane = tid & 63;
    const int l16  = lane & 15;
    const int kg   = lane >> 4;
    const size_t base = (size_t)((b << 4) + h) * SEQ * HDIM;
    const int gq = q0 + w * 16 + l16;

    // Q fragments (B-operand): row=l16=query, k-elems = kw*32 + kg*8 .. +8
    short8 qf[4];
#pragma unroll
    for (int kw = 0; kw < 4; ++kw)
        qf[kw] = *(const short8*)(Qg + base + (size_t)gq * HDIM + kw * 32 + kg * 8);

    f32x4 acc_o[8];
#pragma unroll
    for (int db = 0; db < 8; ++db) acc_o[db] = (f32x4)0.f;
    float m = -1e30f, l = 0.f;

    for (int kt = 0; kt < 10; ++kt) {
        const int gk0 = q0 - 512 + kt * 64;
        if (gk0 < 0) continue;  // tiles are 64-aligned; uniform skip

        // ---- stage K (1024 16B chunks) and Vt (1024 chunks) ----
#pragma unroll
        for (int u = 0; u < 2; ++u) {
            {   // K: row=key-local (id>>4), 16 chunks/row, swizzle ch^(row&7)
                const int id  = u * 512 + w * 64 + lane;
                const int row = id >> 4, ch = id & 15;
                const char* g = (const char*)(Kg + base + (size_t)(gk0 + row) * HDIM
                                              + ((ch ^ (row & 7)) << 3));
                unsigned int lb = __builtin_amdgcn_readfirstlane(
                    (unsigned int)(uintptr_t)(lds + u * 8192 + w * 1024));
                asm volatile("s_mov_b32 m0, %0\n\t"
                             "global_load_lds_dwordx4 %1, off"
                             :: "s"(lb), "v"(g) : "memory");
            }
            {   // Vt: row=d (id>>3), 8 chunks/row, swizzle ch^(d&7)
                const int id  = u * 512 + w * 64 + lane;
                const int d   = id >> 3, ch = id & 7;
                const char* g = (const char*)(Vtg + base + (size_t)d * SEQ + gk0
                                              + ((ch ^ (d & 7)) << 3));
                unsigned int lb = __builtin_amdgcn_readfirstlane(
                    (unsigned int)(uintptr_t)(lds + 16384 + u * 8192 + w * 1024));
                asm volatile("s_mov_b32 m0, %0\n\t"
                             "global_load_lds_dwordx4 %1, off"
                             :: "s"(lb), "v"(g) : "memory");
            }
        }
        asm volatile("s_waitcnt vmcnt(0)" ::: "memory");
        __syncthreads();

        const int qlo = q0 + w * 16;                 // wave's query range
        const bool active = (gk0 <= qlo + 15) && (gk0 + 63 >= qlo - 512);
        if (active) {
            // ---- QK^T ----
            f32x4 s4[4];
#pragma unroll
            for (int kb = 0; kb < 4; ++kb) s4[kb] = (f32x4)0.f;
#pragma unroll
            for (int kw = 0; kw < 4; ++kw)
#pragma unroll
                for (int kb = 0; kb < 4; ++kb) {
                    short8 kf = *(const short8*)(lds + (kb * 16 + l16) * 256
                                                 + (((kw * 4 + kg) ^ (l16 & 7)) << 4));
                    s4[kb] = __builtin_amdgcn_mfma_f32_16x16x32_bf16(
                        kf, qf[kw], s4[kb], 0, 0, 0);
                }

            // ---- masked online softmax (log2 domain) ----
            const int dq = gq - gk0;
            float p[4][4];
            float tm = -1e30f;
#pragma unroll
            for (int kb = 0; kb < 4; ++kb)
#pragma unroll
                for (int r = 0; r < 4; ++r) {
                    const int koff = kb * 16 + kg * 4 + r;
                    const bool valid = (koff <= dq) && (koff >= dq - 512);
                    const float sv = valid ? s4[kb][r] * SCL2E : -1e30f;
                    p[kb][r] = sv;
                    tm = fmaxf(tm, sv);
                }
            tm = fmaxf(tm, __shfl_xor(tm, 16));
            tm = fmaxf(tm, __shfl_xor(tm, 32));
            const float mn   = fmaxf(m, tm);
            const float corr = __builtin_amdgcn_exp2f(m - mn);  // m=-1e30 -> 0
            m = mn;
            l *= corr;
            float cr[4];
#pragma unroll
            for (int r = 0; r < 4; ++r) cr[r] = __shfl(corr, kg * 4 + r);
#pragma unroll
            for (int db = 0; db < 8; ++db)
#pragma unroll
                for (int r = 0; r < 4; ++r) acc_o[db][r] *= cr[r];

            float ts = 0.f;
#pragma unroll
            for (int kb = 0; kb < 4; ++kb)
#pragma unroll
                for (int r = 0; r < 4; ++r) {
                    const float pv = (p[kb][r] > -1e29f)
                                         ? __builtin_amdgcn_exp2f(p[kb][r] - m) : 0.f;
                    p[kb][r] = pv;
                    ts += pv;
                }
            ts += __shfl_xor(ts, 16);
            ts += __shfl_xor(ts, 32);
            l += ts;

            // ---- P -> bf16 A-frags (pure-local thanks to sigma) ----
            unsigned int dw[4][2];
#pragma unroll
            for (int kb = 0; kb < 4; ++kb) {
                dw[kb][0] = cvt_pk_bf16(p[kb][0], p[kb][1]);
                dw[kb][1] = cvt_pk_bf16(p[kb][2], p[kb][3]);
            }
            // ---- PV ----
#pragma unroll
            for (int w2 = 0; w2 < 2; ++w2) {
                union { unsigned int u[4]; short8 v; } pu;
                pu.u[0] = dw[2 * w2][0];     pu.u[1] = dw[2 * w2][1];
                pu.u[2] = dw[2 * w2 + 1][0]; pu.u[3] = dw[2 * w2 + 1][1];
#pragma unroll
                for (int db = 0; db < 8; ++db) {
                    short8 vf = *(const short8*)(lds + 16384 + (db * 16 + l16) * 128
                                                 + (((w2 * 4 + kg) ^ (l16 & 7)) << 4));
                    acc_o[db] = __builtin_amdgcn_mfma_f32_16x16x32_bf16(
                        pu.v, vf, acc_o[db], 0, 0, 0);
                }
            }
        }
        __syncthreads();
    }

    // ---- epilogue: normalize + store bf16 ----
    const float inv = 1.0f / l;
    float li[4];
#pragma unroll
    for (int r = 0; r < 4; ++r) li[r] = __shfl(inv, kg * 4 + r);
#pragma unroll
    for (int db = 0; db < 8; ++db)
#pragma unroll
        for (int r = 0; r < 4; ++r) {
            const int gqr = q0 + w * 16 + kg * 4 + r;
            O[((size_t)b * SEQ + gqr) * EMBED + h * HDIM + db * 16 + l16] =
                f2bf(acc_o[db][r] * li[r]);
        }
}

// ---------------------------------------------------------------------------
extern "C" void kernel_launch(void* const* d_in, const int* in_sizes, int n_in,
                              void* d_out, int out_size, void* d_ws, size_t ws_size,
                              hipStream_t stream)
{
    const float* x     = (const float*)d_in[0];
    const float* w_qkv = (const float*)d_in[1];
    const float* w_out = (const float*)d_in[2];
    float* out = (float*)d_out;

    char* ws = (char*)d_ws;
    unsigned short* xb    = (unsigned short*)(ws);
    unsigned short* wqkvb = (unsigned short*)(ws + 33554432);
    unsigned short* woutb = (unsigned short*)(ws + 58720256);
    unsigned short* qb    = (unsigned short*)(ws + 67108864);
    unsigned short* kb    = (unsigned short*)(ws + 100663296);
    unsigned short* vtb   = (unsigned short*)(ws + 134217728);
    unsigned short* attnb = (unsigned short*)(ws + 167772160);

    const int M = BATCH * SEQ;  // 8192
    dim3 blk(256);

    hipLaunchKernelGGL(cast_bf16_kernel, dim3(NELEM / 8 / 256), blk, 0, stream,
                       x, xb, NELEM / 8);
    hipLaunchKernelGGL(cast_bf16_kernel, dim3(3 * EMBED * EMBED / 8 / 256), blk, 0, stream,
                       w_qkv, wqkvb, 3 * EMBED * EMBED / 8);
    hipLaunchKernelGGL(cast_bf16_kernel, dim3(EMBED * EMBED / 8 / 256), blk, 0, stream,
                       w_out, woutb, EMBED * EMBED / 8);

    // Q,K projection: A = x [8192,2048], B = Wqk rows 0..4095
    hipLaunchKernelGGL((gemm_bf16_kernel<1>), dim3(32, 64), blk, 0, stream,
                       xb, wqkvb, (float*)nullptr, qb, kb, M, 2 * EMBED, EMBED);

    // V^T projection: A = Wv [2048,2048], B = x [8192,2048] -> vt [B,H,128,S]
    hipLaunchKernelGGL((gemm_bf16_kernel<2>), dim3(64, 16), blk, 0, stream,
                       wqkvb + (size_t)2 * EMBED * EMBED, xb, (float*)nullptr,
                       vtb, (unsigned short*)nullptr, EMBED, M, EMBED);

    // attention
    hipLaunchKernelGGL(swa_mfma_kernel, dim3(BATCH * HEADS * (SEQ / 128)), dim3(512),
                       0, stream, qb, kb, vtb, attnb);

    // out projection
    hipLaunchKernelGGL((gemm_bf16_kernel<0>), dim3(16, 64), blk, 0, stream,
                       attnb, woutb, out, (unsigned short*)nullptr,
                       (unsigned short*)nullptr, M, EMBED, EMBED);
}

// Round 5
// 404.130 us; speedup vs baseline: 14.2140x; 1.1291x over previous
//
#include <hip/hip_runtime.h>
#include <hip/hip_bf16.h>
#include <math.h>

// Stage 0: cast x, w_qkv, w_out -> bf16
// Stage 1a: 256^2 8-phase bf16 MFMA GEMM (x * Wqk^T) -> q,k bf16 [B,H,S,128]
// Stage 1b: same structure (Wv * x^T) -> vt bf16 [B,H,128,S], sigma baked in
// Stage 2: MFMA flash attention (window=512) -> attn bf16 [B,S,E]
// Stage 3: 256^2 8-phase bf16 MFMA out-proj GEMM -> d_out fp32
//
// sigma: within each 64-key tile, contraction slot c = (w:1,g:2,t:1,r:2) holds
// key (w:1,t:1,g:2,r:2) -> each lane's PV A-fragment is built purely from its
// own QK^T outputs (zero cross-lane traffic for P).

#define SEQ   4096
#define BATCH 2
#define EMBED 2048
#define HEADS 16
#define HDIM  128
#define NELEM (BATCH * SEQ * EMBED)  // 16777216
#define SCL2E (0.088388347648318447f * 1.4426950408889634f)  // 1/sqrt(128)*log2(e)

typedef __attribute__((ext_vector_type(8))) short short8;
typedef __attribute__((ext_vector_type(4))) float f32x4;

__device__ __forceinline__ unsigned short f2bf(float f) {
    unsigned int u = __float_as_uint(f);
    u = (u + 0x7fff + ((u >> 16) & 1)) >> 16;  // round-to-nearest-even
    return (unsigned short)u;
}

__device__ __forceinline__ unsigned int cvt_pk_bf16(float a, float b) {
    unsigned int r;
    asm volatile("v_cvt_pk_bf16_f32 %0, %1, %2" : "=v"(r) : "v"(a), "v"(b));
    return r;
}

// ---------------------------------------------------------------------------
__global__ void cast_bf16_kernel(const float* __restrict__ src,
                                 unsigned short* __restrict__ dst, int n8)
{
    const int i = blockIdx.x * blockDim.x + threadIdx.x;
    if (i >= n8) return;
    const float4 v0 = ((const float4*)src)[2 * i];
    const float4 v1 = ((const float4*)src)[2 * i + 1];
    union { unsigned short us[8]; uint4 u4; } o;
    o.us[0] = f2bf(v0.x); o.us[1] = f2bf(v0.y); o.us[2] = f2bf(v0.z); o.us[3] = f2bf(v0.w);
    o.us[4] = f2bf(v1.x); o.us[5] = f2bf(v1.y); o.us[6] = f2bf(v1.z); o.us[7] = f2bf(v1.w);
    ((uint4*)dst)[i] = o.u4;
}

// ---------------------------------------------------------------------------
// 256x256 8-phase bf16 NT-GEMM: C[M,N] = A[M,K]*B[N,K]^T, fp32 accum.
// 512 threads = 8 waves (2M x 4N); per-wave 128x64 output (acc[8][4] f32x4).
// BK=64, 2x double-buffered LDS (128 KiB). Per K-tile: 4 phases, each
// {ds_read subtile || stage 1 half-tile (2x global_load_lds) || barrier ||
//  setprio(1) 16 MFMA setprio(0) || barrier}; counted vmcnt(4) once per tile.
// Stage slots: ph1:HA0(t+1) ph2:HA1(t+1) ph3:HB0(t+2) ph4:HB1(t+2) — each
// target region is dead >=1 full barrier interval before the stage issues.
// MODE 0: C fp32 [M,N];  MODE 1: scatter bf16 q/k [B,H,S,128];
// MODE 2: scatter bf16 vt [B,H,128,S] with sigma permutation.
// ---------------------------------------------------------------------------
template <int MODE>
__global__ __launch_bounds__(512, 2)
void gemm256_kernel(const unsigned short* __restrict__ A,
                    const unsigned short* __restrict__ B,
                    float* __restrict__ C,
                    unsigned short* __restrict__ P0,
                    unsigned short* __restrict__ P1,
                    int M, int N, int K)
{
    // bufA[p] @ p*65536 (256 rows x 128B); bufB[p] @ 32768 + p*65536
    __shared__ __align__(16) char lds[131072];

    const int tid  = threadIdx.x;
    const int lane = tid & 63;
    const int w    = tid >> 6;       // 0..7
    const int wm   = w >> 2;         // 0..1
    const int wn   = w & 3;          // 0..3
    const int l16  = lane & 15;
    const int kg   = lane >> 4;

    // XCD-aware block swizzle (nwg % 8 == 0 for all our grids)
    const int nwg  = gridDim.x * gridDim.y;
    const int bidl = blockIdx.y * gridDim.x + blockIdx.x;
    const int cpx  = nwg >> 3;
    const int swzb = (bidl & 7) * cpx + (bidl >> 3);
    const int m0   = (swzb / gridDim.x) * 256;
    const int n0   = (swzb % gridDim.x) * 256;

    // staging geometry: load u covers rows u*64 + w*8 + (lane>>3), chunk lane&7;
    // source chunk pre-swizzled so LDS[row][ch] = global[row][ch ^ (row&7)].
    const int srow = w * 8 + (lane >> 3);
    const int sch8 = ((lane & 7) ^ (lane >> 3)) * 8;

    auto stage = [&](const unsigned short* X, int rowbase, int t2, int ldsbase) {
#pragma unroll
        for (int u = 0; u < 2; ++u) {
            const unsigned short* g = X + (size_t)(rowbase + u * 64 + srow) * K
                                      + t2 * 64 + sch8;
            unsigned int lb = __builtin_amdgcn_readfirstlane(
                (unsigned int)(uintptr_t)(lds + ldsbase + u * 8192 + w * 1024));
            asm volatile("s_mov_b32 m0, %0\n\t"
                         "global_load_lds_dwordx4 %1, off"
                         :: "s"(lb), "v"(g) : "memory");
        }
    };
    auto rdA = [&](int p, int mf, int ks) -> short8 {
        return *(const short8*)(lds + p * 65536 + (wm * 128 + mf * 16 + l16) * 128
                                + (((ks * 4 + kg) ^ (l16 & 7)) << 4));
    };
    auto rdB = [&](int p, int nf, int ks) -> short8 {
        return *(const short8*)(lds + 32768 + p * 65536
                                + (wn * 64 + nf * 16 + l16) * 128
                                + (((ks * 4 + kg) ^ (l16 & 7)) << 4));
    };

    f32x4 acc[8][4];
#pragma unroll
    for (int i = 0; i < 8; ++i)
#pragma unroll
        for (int j = 0; j < 4; ++j) acc[i][j] = (f32x4)0.f;

    const int NT = K >> 6;  // K-tiles of 64

    // prologue: HB0(0) HB1(0) HA0(0) HA1(0) HB0(1) HB1(1); wait all but HB*(1)
    stage(B, n0 + 0,   0, 32768);
    stage(B, n0 + 128, 0, 32768 + 16384);
    stage(A, m0 + 0,   0, 0);
    stage(A, m0 + 128, 0, 16384);
    stage(B, n0 + 0,   1, 32768 + 65536);
    stage(B, n0 + 128, 1, 32768 + 65536 + 16384);
    asm volatile("s_waitcnt vmcnt(4)" ::: "memory");
    asm volatile("s_barrier" ::: "memory");

    short8 bfr[4][2];
    for (int t = 0; t < NT; ++t) {
        const int p = t & 1;
#pragma unroll
        for (int q = 0; q < 4; ++q) {
            short8 afr[2][2];
#pragma unroll
            for (int i = 0; i < 2; ++i)
#pragma unroll
                for (int ks = 0; ks < 2; ++ks)
                    afr[i][ks] = rdA(p, 2 * q + i, ks);
            if (q == 0) {
#pragma unroll
                for (int nf = 0; nf < 4; ++nf)
#pragma unroll
                    for (int ks = 0; ks < 2; ++ks)
                        bfr[nf][ks] = rdB(p, nf, ks);
            }
            // stage slot (targets dead >=1 barrier interval; see header)
            if (q == 0)      { if (t + 1 < NT) stage(A, m0 + 0,   t + 1, (p ^ 1) * 65536); }
            else if (q == 1) { if (t + 1 < NT) stage(A, m0 + 128, t + 1, (p ^ 1) * 65536 + 16384); }
            else if (q == 2) { if (t + 2 < NT) stage(B, n0 + 0,   t + 2, p * 65536 + 32768); }
            else             { if (t + 2 < NT) stage(B, n0 + 128, t + 2, p * 65536 + 32768 + 16384); }

            asm volatile("s_barrier" ::: "memory");
            __builtin_amdgcn_s_setprio(1);
#pragma unroll
            for (int i = 0; i < 2; ++i)
#pragma unroll
                for (int nf = 0; nf < 4; ++nf)
#pragma unroll
                    for (int ks = 0; ks < 2; ++ks)
                        acc[2 * q + i][nf] = __builtin_amdgcn_mfma_f32_16x16x32_bf16(
                            afr[i][ks], bfr[nf][ks], acc[2 * q + i][nf], 0, 0, 0);
            __builtin_amdgcn_s_setprio(0);
            if (q == 3) {
                // once per K-tile: leave HB*(t+2) (4 loads) in flight
                if (t >= NT - 2) asm volatile("s_waitcnt vmcnt(0)" ::: "memory");
                else             asm volatile("s_waitcnt vmcnt(4)" ::: "memory");
            }
            asm volatile("s_barrier" ::: "memory");
        }
    }

    // epilogue: frag (fi,nf,r) -> row m0+wm*128+fi*16+kg*4+r, col n0+wn*64+nf*16+l16
    if (MODE == 1) {
        const int cb = n0 + wn * 64;          // 64-col wave tile: one head slice
        unsigned short* dst = (cb >> 11) ? P1 : P0;
        const int h  = (cb >> 7) & 15;
        const int db = cb & 127;
#pragma unroll
        for (int fi = 0; fi < 8; ++fi)
#pragma unroll
            for (int r = 0; r < 4; ++r) {
                const int mrow = m0 + wm * 128 + fi * 16 + kg * 4 + r;
                const int b = mrow >> 12, s = mrow & 4095;
                unsigned short* drow = dst + ((size_t)((b << 4) + h) * SEQ + s) * HDIM
                                       + db + l16;
#pragma unroll
                for (int nf = 0; nf < 4; ++nf) drow[nf * 16] = f2bf(acc[fi][nf][r]);
            }
    } else if (MODE == 2) {
#pragma unroll
        for (int fi = 0; fi < 8; ++fi)
#pragma unroll
            for (int r = 0; r < 4; ++r) {
                const int mrow = m0 + wm * 128 + fi * 16 + kg * 4 + r;
                const int h = mrow >> 7, d = mrow & 127;
#pragma unroll
                for (int nf = 0; nf < 4; ++nf) {
                    const int col = n0 + wn * 64 + nf * 16 + l16;
                    const int b = col >> 12, s = col & 4095;
                    const int sl = s & 63;
                    const int c = (sl & 0x23) | ((sl & 0x0C) << 1) | ((sl & 0x10) >> 2);
                    P0[((size_t)((b << 4) + h) * HDIM + d) * SEQ + (s & ~63) + c] =
                        f2bf(acc[fi][nf][r]);
                }
            }
    } else {
#pragma unroll
        for (int fi = 0; fi < 8; ++fi)
#pragma unroll
            for (int r = 0; r < 4; ++r) {
                float* crow = C + (size_t)(m0 + wm * 128 + fi * 16 + kg * 4 + r) * N
                              + n0 + wn * 64 + l16;
#pragma unroll
                for (int nf = 0; nf < 4; ++nf) crow[nf * 16] = acc[fi][nf][r];
            }
    }
}

// ---------------------------------------------------------------------------
// MFMA flash attention (validated R4). Block = 512 threads = 8 waves; 128
// queries per block. K tile [64 keys][128 d] @ lds+0; Vt tile [128 d][64
// sigma-keys] @ +16384. Swapped QK^T; P built lane-locally thanks to sigma.
// ---------------------------------------------------------------------------
__global__ __launch_bounds__(512)
void swa_mfma_kernel(const unsigned short* __restrict__ Qg,
                     const unsigned short* __restrict__ Kg,
                     const unsigned short* __restrict__ Vtg,
                     unsigned short* __restrict__ O /* bf16 [B,S,E] */)
{
    __shared__ __align__(16) char lds[32768];

    const int bid = blockIdx.x;
    const int qt  = bid & 31;
    const int h   = (bid >> 5) & 15;
    const int b   = bid >> 9;
    const int q0  = qt * 128;
    const int tid  = threadIdx.x;
    const int w    = tid >> 6;
    const int lane = tid & 63;
    const int l16  = lane & 15;
    const int kg   = lane >> 4;
    const size_t base = (size_t)((b << 4) + h) * SEQ * HDIM;
    const int gq = q0 + w * 16 + l16;

    short8 qf[4];
#pragma unroll
    for (int kw = 0; kw < 4; ++kw)
        qf[kw] = *(const short8*)(Qg + base + (size_t)gq * HDIM + kw * 32 + kg * 8);

    f32x4 acc_o[8];
#pragma unroll
    for (int db = 0; db < 8; ++db) acc_o[db] = (f32x4)0.f;
    float m = -1e30f, l = 0.f;

    for (int kt = 0; kt < 10; ++kt) {
        const int gk0 = q0 - 512 + kt * 64;
        if (gk0 < 0) continue;

#pragma unroll
        for (int u = 0; u < 2; ++u) {
            {   // K: row=key (id>>4), 16 chunks/row, swizzle ch^(row&7)
                const int id  = u * 512 + w * 64 + lane;
                const int row = id >> 4, ch = id & 15;
                const char* g = (const char*)(Kg + base + (size_t)(gk0 + row) * HDIM
                                              + ((ch ^ (row & 7)) << 3));
                unsigned int lb = __builtin_amdgcn_readfirstlane(
                    (unsigned int)(uintptr_t)(lds + u * 8192 + w * 1024));
                asm volatile("s_mov_b32 m0, %0\n\t"
                             "global_load_lds_dwordx4 %1, off"
                             :: "s"(lb), "v"(g) : "memory");
            }
            {   // Vt: row=d (id>>3), 8 chunks/row, swizzle ch^(d&7)
                const int id  = u * 512 + w * 64 + lane;
                const int d   = id >> 3, ch = id & 7;
                const char* g = (const char*)(Vtg + base + (size_t)d * SEQ + gk0
                                              + ((ch ^ (d & 7)) << 3));
                unsigned int lb = __builtin_amdgcn_readfirstlane(
                    (unsigned int)(uintptr_t)(lds + 16384 + u * 8192 + w * 1024));
                asm volatile("s_mov_b32 m0, %0\n\t"
                             "global_load_lds_dwordx4 %1, off"
                             :: "s"(lb), "v"(g) : "memory");
            }
        }
        asm volatile("s_waitcnt vmcnt(0)" ::: "memory");
        __syncthreads();

        const int qlo = q0 + w * 16;
        const bool active = (gk0 <= qlo + 15) && (gk0 + 63 >= qlo - 512);
        if (active) {
            f32x4 s4[4];
#pragma unroll
            for (int kb = 0; kb < 4; ++kb) s4[kb] = (f32x4)0.f;
#pragma unroll
            for (int kw = 0; kw < 4; ++kw)
#pragma unroll
                for (int kb = 0; kb < 4; ++kb) {
                    short8 kf = *(const short8*)(lds + (kb * 16 + l16) * 256
                                                 + (((kw * 4 + kg) ^ (l16 & 7)) << 4));
                    s4[kb] = __builtin_amdgcn_mfma_f32_16x16x32_bf16(
                        kf, qf[kw], s4[kb], 0, 0, 0);
                }

            const int dq = gq - gk0;
            float p[4][4];
            float tm = -1e30f;
#pragma unroll
            for (int kb = 0; kb < 4; ++kb)
#pragma unroll
                for (int r = 0; r < 4; ++r) {
                    const int koff = kb * 16 + kg * 4 + r;
                    const bool valid = (koff <= dq) && (koff >= dq - 512);
                    const float sv = valid ? s4[kb][r] * SCL2E : -1e30f;
                    p[kb][r] = sv;
                    tm = fmaxf(tm, sv);
                }
            tm = fmaxf(tm, __shfl_xor(tm, 16));
            tm = fmaxf(tm, __shfl_xor(tm, 32));
            const float mn   = fmaxf(m, tm);
            const float corr = __builtin_amdgcn_exp2f(m - mn);
            m = mn;
            l *= corr;
            float cr[4];
#pragma unroll
            for (int r = 0; r < 4; ++r) cr[r] = __shfl(corr, kg * 4 + r);
#pragma unroll
            for (int db = 0; db < 8; ++db)
#pragma unroll
                for (int r = 0; r < 4; ++r) acc_o[db][r] *= cr[r];

            float ts = 0.f;
#pragma unroll
            for (int kb = 0; kb < 4; ++kb)
#pragma unroll
                for (int r = 0; r < 4; ++r) {
                    const float pv = (p[kb][r] > -1e29f)
                                         ? __builtin_amdgcn_exp2f(p[kb][r] - m) : 0.f;
                    p[kb][r] = pv;
                    ts += pv;
                }
            ts += __shfl_xor(ts, 16);
            ts += __shfl_xor(ts, 32);
            l += ts;

            unsigned int dw[4][2];
#pragma unroll
            for (int kb = 0; kb < 4; ++kb) {
                dw[kb][0] = cvt_pk_bf16(p[kb][0], p[kb][1]);
                dw[kb][1] = cvt_pk_bf16(p[kb][2], p[kb][3]);
            }
#pragma unroll
            for (int w2 = 0; w2 < 2; ++w2) {
                union { unsigned int u[4]; short8 v; } pu;
                pu.u[0] = dw[2 * w2][0];     pu.u[1] = dw[2 * w2][1];
                pu.u[2] = dw[2 * w2 + 1][0]; pu.u[3] = dw[2 * w2 + 1][1];
#pragma unroll
                for (int db = 0; db < 8; ++db) {
                    short8 vf = *(const short8*)(lds + 16384 + (db * 16 + l16) * 128
                                                 + (((w2 * 4 + kg) ^ (l16 & 7)) << 4));
                    acc_o[db] = __builtin_amdgcn_mfma_f32_16x16x32_bf16(
                        pu.v, vf, acc_o[db], 0, 0, 0);
                }
            }
        }
        __syncthreads();
    }

    const float inv = 1.0f / l;
    float li[4];
#pragma unroll
    for (int r = 0; r < 4; ++r) li[r] = __shfl(inv, kg * 4 + r);
#pragma unroll
    for (int db = 0; db < 8; ++db)
#pragma unroll
        for (int r = 0; r < 4; ++r) {
            const int gqr = q0 + w * 16 + kg * 4 + r;
            O[((size_t)b * SEQ + gqr) * EMBED + h * HDIM + db * 16 + l16] =
                f2bf(acc_o[db][r] * li[r]);
        }
}

// ---------------------------------------------------------------------------
extern "C" void kernel_launch(void* const* d_in, const int* in_sizes, int n_in,
                              void* d_out, int out_size, void* d_ws, size_t ws_size,
                              hipStream_t stream)
{
    const float* x     = (const float*)d_in[0];
    const float* w_qkv = (const float*)d_in[1];
    const float* w_out = (const float*)d_in[2];
    float* out = (float*)d_out;

    char* ws = (char*)d_ws;
    unsigned short* xb    = (unsigned short*)(ws);
    unsigned short* wqkvb = (unsigned short*)(ws + 33554432);
    unsigned short* woutb = (unsigned short*)(ws + 58720256);
    unsigned short* qb    = (unsigned short*)(ws + 67108864);
    unsigned short* kb    = (unsigned short*)(ws + 100663296);
    unsigned short* vtb   = (unsigned short*)(ws + 134217728);
    unsigned short* attnb = (unsigned short*)(ws + 167772160);

    const int M = BATCH * SEQ;  // 8192
    dim3 blk(256);

    hipLaunchKernelGGL(cast_bf16_kernel, dim3(NELEM / 8 / 256), blk, 0, stream,
                       x, xb, NELEM / 8);
    hipLaunchKernelGGL(cast_bf16_kernel, dim3(3 * EMBED * EMBED / 8 / 256), blk, 0, stream,
                       w_qkv, wqkvb, 3 * EMBED * EMBED / 8);
    hipLaunchKernelGGL(cast_bf16_kernel, dim3(EMBED * EMBED / 8 / 256), blk, 0, stream,
                       w_out, woutb, EMBED * EMBED / 8);

    // Q,K projection: A = x [8192,2048], B = Wqk rows 0..4095 -> grid (16,32)
    hipLaunchKernelGGL((gemm256_kernel<1>), dim3(16, 32), dim3(512), 0, stream,
                       xb, wqkvb, (float*)nullptr, qb, kb, M, 2 * EMBED, EMBED);

    // V^T projection: A = Wv [2048,2048], B = x [8192,2048] -> grid (32,8)
    hipLaunchKernelGGL((gemm256_kernel<2>), dim3(32, 8), dim3(512), 0, stream,
                       wqkvb + (size_t)2 * EMBED * EMBED, xb, (float*)nullptr,
                       vtb, (unsigned short*)nullptr, EMBED, M, EMBED);

    // attention
    hipLaunchKernelGGL(swa_mfma_kernel, dim3(BATCH * HEADS * (SEQ / 128)), dim3(512),
                       0, stream, qb, kb, vtb, attnb);

    // out projection: grid (8,32)
    hipLaunchKernelGGL((gemm256_kernel<0>), dim3(8, 32), dim3(512), 0, stream,
                       attnb, woutb, out, (unsigned short*)nullptr,
                       (unsigned short*)nullptr, M, EMBED, EMBED);
}

// Round 6
// 356.100 us; speedup vs baseline: 16.1312x; 1.1349x over previous
//
#include <hip/hip_runtime.h>
#include <hip/hip_bf16.h>
#include <math.h>

// Stage 0: cast x, w_qkv, w_out -> bf16
// Stage 1a: 256^2 reg-pipelined bf16 MFMA GEMM (x * Wqk^T) -> q,k bf16 [B,H,S,128]
// Stage 1b: same structure (Wv * x^T) -> vt bf16 [B,H,128,S], sigma baked in
// Stage 2: MFMA flash attention (window=512, double-buffered KV) -> attn bf16
// Stage 3: same GEMM -> d_out fp32
//
// GEMM schedule (per K-tile t, parity p, 4 phases; ONE barrier per phase):
//   q0: stage Ah0(t+1)->A[p^1];          bar; read quad1->afrB; MFMA quad0(afrA)
//   q1: stage Ah1(t+1)->A[p^1];          bar; read quad2->afrA; MFMA quad1(afrB)
//   q2: stage Bh0(t+2)->B[p];            bar; read quad3->afrB; MFMA quad2(afrA)
//   q3: stage Bh1(t+2)->B[p]; vmcnt(4);  bar; read t+1 quad0->afrA;
//       MFMA quad3(afrB); late-read bfr(t+1) from B[p^1]
// ds_reads of phase q+1 overlap MFMA of phase q (lgkm deferred by compiler).
// vmcnt(4) leaves B(t+2)'s 4 loads in flight; never drains mid-loop.
// B-buf[p] is dead after t-1/q3's bfr read (register-cached) -> q2 stage safe.
// A-buf[p^1] dead after t-1/q2 read (consumed by t-1/q3 MFMA pre-barrier).

#define SEQ   4096
#define BATCH 2
#define EMBED 2048
#define HEADS 16
#define HDIM  128
#define NELEM (BATCH * SEQ * EMBED)  // 16777216
#define SCL2E (0.088388347648318447f * 1.4426950408889634f)  // 1/sqrt(128)*log2(e)

typedef __attribute__((ext_vector_type(8))) short short8;
typedef __attribute__((ext_vector_type(4))) float f32x4;

__device__ __forceinline__ unsigned short f2bf(float f) {
    unsigned int u = __float_as_uint(f);
    u = (u + 0x7fff + ((u >> 16) & 1)) >> 16;  // round-to-nearest-even
    return (unsigned short)u;
}

__device__ __forceinline__ unsigned int cvt_pk_bf16(float a, float b) {
    unsigned int r;
    asm volatile("v_cvt_pk_bf16_f32 %0, %1, %2" : "=v"(r) : "v"(a), "v"(b));
    return r;
}

// ---------------------------------------------------------------------------
__global__ void cast_bf16_kernel(const float* __restrict__ src,
                                 unsigned short* __restrict__ dst, int n8)
{
    const int i = blockIdx.x * blockDim.x + threadIdx.x;
    if (i >= n8) return;
    const float4 v0 = ((const float4*)src)[2 * i];
    const float4 v1 = ((const float4*)src)[2 * i + 1];
    union { unsigned short us[8]; uint4 u4; } o;
    o.us[0] = f2bf(v0.x); o.us[1] = f2bf(v0.y); o.us[2] = f2bf(v0.z); o.us[3] = f2bf(v0.w);
    o.us[4] = f2bf(v1.x); o.us[5] = f2bf(v1.y); o.us[6] = f2bf(v1.z); o.us[7] = f2bf(v1.w);
    ((uint4*)dst)[i] = o.u4;
}

// ---------------------------------------------------------------------------
// 256x256 bf16 NT-GEMM: C[M,N] = A[M,K]*B[N,K]^T, fp32 accum. 512 thr, 8 waves
// (2M x 4N), per-wave 128x64 (acc[8][4]). BK=64, double-buffered 128 KiB LDS.
// MODE 0: C fp32 [M,N];  MODE 1: scatter bf16 q/k [B,H,S,128];
// MODE 2: scatter bf16 vt [B,H,128,S] with sigma permutation.
// ---------------------------------------------------------------------------
template <int MODE>
__global__ __launch_bounds__(512, 2)
void gemm256_kernel(const unsigned short* __restrict__ A,
                    const unsigned short* __restrict__ B,
                    float* __restrict__ C,
                    unsigned short* __restrict__ P0,
                    unsigned short* __restrict__ P1,
                    int M, int N, int K)
{
    // Abuf[p] @ p*32768; Bbuf[p] @ 65536 + p*32768
    __shared__ __align__(16) char lds[131072];

    const int tid  = threadIdx.x;
    const int lane = tid & 63;
    const int w    = tid >> 6;       // 0..7
    const int wm   = w >> 2;         // 0..1
    const int wn   = w & 3;          // 0..3
    const int l16  = lane & 15;
    const int kg   = lane >> 4;

    // n-major XCD swizzle: each XCD owns a contiguous n-column chunk ->
    // small weight panel stays L2-resident; A streams through L3.
    const int nwg  = gridDim.x * gridDim.y;
    const int bidl = blockIdx.y * gridDim.x + blockIdx.x;
    const int cpx  = nwg >> 3;
    const int swzb = (bidl & 7) * cpx + (bidl >> 3);
    const int MB   = gridDim.y;
    const int n0   = (swzb / MB) * 256;
    const int m0   = (swzb % MB) * 256;

    // staging: per instr u, rows u*64 + w*8 + (lane>>3); source chunk
    // pre-swizzled so LDS[row][ch] = global[row][ch ^ (row&7)].
    const int srow = w * 8 + (lane >> 3);
    const int sch8 = ((lane & 7) ^ (lane >> 3)) * 8;

    auto stage = [&](const unsigned short* X, int rowbase, int t2, int ldsbase) {
#pragma unroll
        for (int u = 0; u < 2; ++u) {
            const unsigned short* g = X + (size_t)(rowbase + u * 64 + srow) * K
                                      + t2 * 64 + sch8;
            unsigned int lb = __builtin_amdgcn_readfirstlane(
                (unsigned int)(uintptr_t)(lds + ldsbase + u * 8192 + w * 1024));
            asm volatile("s_mov_b32 m0, %0\n\t"
                         "global_load_lds_dwordx4 %1, off"
                         :: "s"(lb), "v"(g) : "memory");
        }
    };
    auto rdA = [&](int p, int mf, int ks) -> short8 {
        return *(const short8*)(lds + p * 32768 + (wm * 128 + mf * 16 + l16) * 128
                                + (((ks * 4 + kg) ^ (l16 & 7)) << 4));
    };
    auto rdB = [&](int p, int nf, int ks) -> short8 {
        return *(const short8*)(lds + 65536 + p * 32768
                                + (wn * 64 + nf * 16 + l16) * 128
                                + (((ks * 4 + kg) ^ (l16 & 7)) << 4));
    };

    f32x4 acc[8][4];
#pragma unroll
    for (int i = 0; i < 8; ++i)
#pragma unroll
        for (int j = 0; j < 4; ++j) acc[i][j] = (f32x4)0.f;

    const int NT = K >> 6;

    // prologue: A(0), B(0), B(1); wait all but B(1)'s 4 loads
    stage(A, m0 + 0,   0, 0);
    stage(A, m0 + 128, 0, 16384);
    stage(B, n0 + 0,   0, 65536);
    stage(B, n0 + 128, 0, 65536 + 16384);
    if (NT > 1) {
        stage(B, n0 + 0,   1, 65536 + 32768);
        stage(B, n0 + 128, 1, 65536 + 32768 + 16384);
        asm volatile("s_waitcnt vmcnt(4)" ::: "memory");
    } else {
        asm volatile("s_waitcnt vmcnt(0)" ::: "memory");
    }
    asm volatile("s_barrier" ::: "memory");

    short8 afrA[2][2], afrB[2][2], bfr[4][2];
#pragma unroll
    for (int i = 0; i < 2; ++i)
#pragma unroll
        for (int ks = 0; ks < 2; ++ks) afrA[i][ks] = rdA(0, i, ks);
#pragma unroll
    for (int nf = 0; nf < 4; ++nf)
#pragma unroll
        for (int ks = 0; ks < 2; ++ks) bfr[nf][ks] = rdB(0, nf, ks);

#define MFMA_QUAD(Q, FR)                                                        \
    __builtin_amdgcn_s_setprio(1);                                              \
    _Pragma("unroll")                                                           \
    for (int i = 0; i < 2; ++i)                                                 \
        _Pragma("unroll")                                                       \
        for (int nf = 0; nf < 4; ++nf)                                          \
            _Pragma("unroll")                                                   \
            for (int ks = 0; ks < 2; ++ks)                                      \
                acc[2 * (Q) + i][nf] = __builtin_amdgcn_mfma_f32_16x16x32_bf16( \
                    FR[i][ks], bfr[nf][ks], acc[2 * (Q) + i][nf], 0, 0, 0);     \
    __builtin_amdgcn_s_setprio(0);

    for (int t = 0; t < NT; ++t) {
        const int p = t & 1;
        // ---- phase 0 ----
        if (t + 1 < NT) stage(A, m0 + 0, t + 1, (p ^ 1) * 32768);
        asm volatile("s_barrier" ::: "memory");
#pragma unroll
        for (int i = 0; i < 2; ++i)
#pragma unroll
            for (int ks = 0; ks < 2; ++ks) afrB[i][ks] = rdA(p, 2 + i, ks);
        MFMA_QUAD(0, afrA)
        // ---- phase 1 ----
        if (t + 1 < NT) stage(A, m0 + 128, t + 1, (p ^ 1) * 32768 + 16384);
        asm volatile("s_barrier" ::: "memory");
#pragma unroll
        for (int i = 0; i < 2; ++i)
#pragma unroll
            for (int ks = 0; ks < 2; ++ks) afrA[i][ks] = rdA(p, 4 + i, ks);
        MFMA_QUAD(1, afrB)
        // ---- phase 2 ----
        if (t + 2 < NT) stage(B, n0 + 0, t + 2, 65536 + p * 32768);
        asm volatile("s_barrier" ::: "memory");
#pragma unroll
        for (int i = 0; i < 2; ++i)
#pragma unroll
            for (int ks = 0; ks < 2; ++ks) afrB[i][ks] = rdA(p, 6 + i, ks);
        MFMA_QUAD(2, afrA)
        // ---- phase 3 ----
        if (t + 2 < NT) {
            stage(B, n0 + 128, t + 2, 65536 + p * 32768 + 16384);
            asm volatile("s_waitcnt vmcnt(4)" ::: "memory");
        } else {
            asm volatile("s_waitcnt vmcnt(0)" ::: "memory");
        }
        asm volatile("s_barrier" ::: "memory");
        if (t + 1 < NT) {
#pragma unroll
            for (int i = 0; i < 2; ++i)
#pragma unroll
                for (int ks = 0; ks < 2; ++ks) afrA[i][ks] = rdA(p ^ 1, i, ks);
        }
        MFMA_QUAD(3, afrB)
        if (t + 1 < NT) {
#pragma unroll
            for (int nf = 0; nf < 4; ++nf)
#pragma unroll
                for (int ks = 0; ks < 2; ++ks) bfr[nf][ks] = rdB(p ^ 1, nf, ks);
        }
    }
#undef MFMA_QUAD

    // epilogue: frag (fi,nf,r) -> row m0+wm*128+fi*16+kg*4+r, col n0+wn*64+nf*16+l16
    if (MODE == 1) {
        const int cb = n0 + wn * 64;          // 64-col wave tile: one head slice
        unsigned short* dst = (cb >> 11) ? P1 : P0;
        const int h  = (cb >> 7) & 15;
        const int db = cb & 127;
#pragma unroll
        for (int fi = 0; fi < 8; ++fi)
#pragma unroll
            for (int r = 0; r < 4; ++r) {
                const int mrow = m0 + wm * 128 + fi * 16 + kg * 4 + r;
                const int b = mrow >> 12, s = mrow & 4095;
                unsigned short* drow = dst + ((size_t)((b << 4) + h) * SEQ + s) * HDIM
                                       + db + l16;
#pragma unroll
                for (int nf = 0; nf < 4; ++nf) drow[nf * 16] = f2bf(acc[fi][nf][r]);
            }
    } else if (MODE == 2) {
#pragma unroll
        for (int fi = 0; fi < 8; ++fi)
#pragma unroll
            for (int r = 0; r < 4; ++r) {
                const int mrow = m0 + wm * 128 + fi * 16 + kg * 4 + r;
                const int h = mrow >> 7, d = mrow & 127;
#pragma unroll
                for (int nf = 0; nf < 4; ++nf) {
                    const int col = n0 + wn * 64 + nf * 16 + l16;
                    const int b = col >> 12, s = col & 4095;
                    const int sl = s & 63;
                    const int c = (sl & 0x23) | ((sl & 0x0C) << 1) | ((sl & 0x10) >> 2);
                    P0[((size_t)((b << 4) + h) * HDIM + d) * SEQ + (s & ~63) + c] =
                        f2bf(acc[fi][nf][r]);
                }
            }
    } else {
#pragma unroll
        for (int fi = 0; fi < 8; ++fi)
#pragma unroll
            for (int r = 0; r < 4; ++r) {
                float* crow = C + (size_t)(m0 + wm * 128 + fi * 16 + kg * 4 + r) * N
                              + n0 + wn * 64 + l16;
#pragma unroll
                for (int nf = 0; nf < 4; ++nf) crow[nf * 16] = acc[fi][nf][r];
            }
    }
}

// ---------------------------------------------------------------------------
// MFMA flash attention, double-buffered KV staging. Block = 512 thr = 8 waves;
// 128 queries/block. Per buf: K [64 keys][128 d] @ +0, Vt [128 d][64 sigma-
// keys] @ +16384; bufs @ 0 / 32768. Swapped QK^T; P lane-local via sigma.
// ---------------------------------------------------------------------------
__global__ __launch_bounds__(512)
void swa_mfma_kernel(const unsigned short* __restrict__ Qg,
                     const unsigned short* __restrict__ Kg,
                     const unsigned short* __restrict__ Vtg,
                     unsigned short* __restrict__ O /* bf16 [B,S,E] */)
{
    __shared__ __align__(16) char lds[65536];

    const int bid = blockIdx.x;
    const int qt  = bid & 31;
    const int h   = (bid >> 5) & 15;
    const int b   = bid >> 9;
    const int q0  = qt * 128;
    const int tid  = threadIdx.x;
    const int w    = tid >> 6;
    const int lane = tid & 63;
    const int l16  = lane & 15;
    const int kg   = lane >> 4;
    const size_t base = (size_t)((b << 4) + h) * SEQ * HDIM;
    const int gq = q0 + w * 16 + l16;

    short8 qf[4];
#pragma unroll
    for (int kw = 0; kw < 4; ++kw)
        qf[kw] = *(const short8*)(Qg + base + (size_t)gq * HDIM + kw * 32 + kg * 8);

    f32x4 acc_o[8];
#pragma unroll
    for (int db = 0; db < 8; ++db) acc_o[db] = (f32x4)0.f;
    float m = -1e30f, l = 0.f;

    auto stageKV = [&](int kt, int buf) {
        const int gk0 = q0 - 512 + kt * 64;
#pragma unroll
        for (int u = 0; u < 2; ++u) {
            {   // K: row=key (id>>4), 16 chunks/row, swizzle ch^(row&7)
                const int id  = u * 512 + w * 64 + lane;
                const int row = id >> 4, ch = id & 15;
                const char* g = (const char*)(Kg + base + (size_t)(gk0 + row) * HDIM
                                              + ((ch ^ (row & 7)) << 3));
                unsigned int lb = __builtin_amdgcn_readfirstlane(
                    (unsigned int)(uintptr_t)(lds + buf * 32768 + u * 8192 + w * 1024));
                asm volatile("s_mov_b32 m0, %0\n\t"
                             "global_load_lds_dwordx4 %1, off"
                             :: "s"(lb), "v"(g) : "memory");
            }
            {   // Vt: row=d (id>>3), 8 chunks/row, swizzle ch^(d&7)
                const int id  = u * 512 + w * 64 + lane;
                const int d   = id >> 3, ch = id & 7;
                const char* g = (const char*)(Vtg + base + (size_t)d * SEQ + gk0
                                              + ((ch ^ (d & 7)) << 3));
                unsigned int lb = __builtin_amdgcn_readfirstlane(
                    (unsigned int)(uintptr_t)(lds + buf * 32768 + 16384
                                              + u * 8192 + w * 1024));
                asm volatile("s_mov_b32 m0, %0\n\t"
                             "global_load_lds_dwordx4 %1, off"
                             :: "s"(lb), "v"(g) : "memory");
            }
        }
    };

    const int kt_start = (qt < 4) ? (8 - 2 * qt) : 0;
    stageKV(kt_start, 0);
    int cur = 0;

    for (int kt = kt_start; kt < 10; ++kt) {
        asm volatile("s_waitcnt vmcnt(0)" ::: "memory");
        __syncthreads();
        if (kt + 1 < 10) stageKV(kt + 1, cur ^ 1);

        const int gk0 = q0 - 512 + kt * 64;
        const char* ldsb = lds + cur * 32768;
        const int qlo = q0 + w * 16;
        const bool active = (gk0 <= qlo + 15) && (gk0 + 63 >= qlo - 512);
        if (active) {
            f32x4 s4[4];
#pragma unroll
            for (int kb = 0; kb < 4; ++kb) s4[kb] = (f32x4)0.f;
#pragma unroll
            for (int kw = 0; kw < 4; ++kw)
#pragma unroll
                for (int kb = 0; kb < 4; ++kb) {
                    short8 kf = *(const short8*)(ldsb + (kb * 16 + l16) * 256
                                                 + (((kw * 4 + kg) ^ (l16 & 7)) << 4));
                    s4[kb] = __builtin_amdgcn_mfma_f32_16x16x32_bf16(
                        kf, qf[kw], s4[kb], 0, 0, 0);
                }

            const int dq = gq - gk0;
            float p[4][4];
            float tm = -1e30f;
#pragma unroll
            for (int kb = 0; kb < 4; ++kb)
#pragma unroll
                for (int r = 0; r < 4; ++r) {
                    const int koff = kb * 16 + kg * 4 + r;
                    const bool valid = (koff <= dq) && (koff >= dq - 512);
                    const float sv = valid ? s4[kb][r] * SCL2E : -1e30f;
                    p[kb][r] = sv;
                    tm = fmaxf(tm, sv);
                }
            tm = fmaxf(tm, __shfl_xor(tm, 16));
            tm = fmaxf(tm, __shfl_xor(tm, 32));
            const float mn   = fmaxf(m, tm);
            const float corr = __builtin_amdgcn_exp2f(m - mn);
            m = mn;
            l *= corr;
            float cr[4];
#pragma unroll
            for (int r = 0; r < 4; ++r) cr[r] = __shfl(corr, kg * 4 + r);
#pragma unroll
            for (int db = 0; db < 8; ++db)
#pragma unroll
                for (int r = 0; r < 4; ++r) acc_o[db][r] *= cr[r];

            float ts = 0.f;
#pragma unroll
            for (int kb = 0; kb < 4; ++kb)
#pragma unroll
                for (int r = 0; r < 4; ++r) {
                    const float pv = (p[kb][r] > -1e29f)
                                         ? __builtin_amdgcn_exp2f(p[kb][r] - m) : 0.f;
                    p[kb][r] = pv;
                    ts += pv;
                }
            ts += __shfl_xor(ts, 16);
            ts += __shfl_xor(ts, 32);
            l += ts;

            unsigned int dw[4][2];
#pragma unroll
            for (int kb = 0; kb < 4; ++kb) {
                dw[kb][0] = cvt_pk_bf16(p[kb][0], p[kb][1]);
                dw[kb][1] = cvt_pk_bf16(p[kb][2], p[kb][3]);
            }
#pragma unroll
            for (int w2 = 0; w2 < 2; ++w2) {
                union { unsigned int u[4]; short8 v; } pu;
                pu.u[0] = dw[2 * w2][0];     pu.u[1] = dw[2 * w2][1];
                pu.u[2] = dw[2 * w2 + 1][0]; pu.u[3] = dw[2 * w2 + 1][1];
#pragma unroll
                for (int db = 0; db < 8; ++db) {
                    short8 vf = *(const short8*)(ldsb + 16384 + (db * 16 + l16) * 128
                                                 + (((w2 * 4 + kg) ^ (l16 & 7)) << 4));
                    acc_o[db] = __builtin_amdgcn_mfma_f32_16x16x32_bf16(
                        pu.v, vf, acc_o[db], 0, 0, 0);
                }
            }
        }
        cur ^= 1;
    }

    const float inv = 1.0f / l;
    float li[4];
#pragma unroll
    for (int r = 0; r < 4; ++r) li[r] = __shfl(inv, kg * 4 + r);
#pragma unroll
    for (int db = 0; db < 8; ++db)
#pragma unroll
        for (int r = 0; r < 4; ++r) {
            const int gqr = q0 + w * 16 + kg * 4 + r;
            O[((size_t)b * SEQ + gqr) * EMBED + h * HDIM + db * 16 + l16] =
                f2bf(acc_o[db][r] * li[r]);
        }
}

// ---------------------------------------------------------------------------
extern "C" void kernel_launch(void* const* d_in, const int* in_sizes, int n_in,
                              void* d_out, int out_size, void* d_ws, size_t ws_size,
                              hipStream_t stream)
{
    const float* x     = (const float*)d_in[0];
    const float* w_qkv = (const float*)d_in[1];
    const float* w_out = (const float*)d_in[2];
    float* out = (float*)d_out;

    char* ws = (char*)d_ws;
    unsigned short* xb    = (unsigned short*)(ws);
    unsigned short* wqkvb = (unsigned short*)(ws + 33554432);
    unsigned short* woutb = (unsigned short*)(ws + 58720256);
    unsigned short* qb    = (unsigned short*)(ws + 67108864);
    unsigned short* kb    = (unsigned short*)(ws + 100663296);
    unsigned short* vtb   = (unsigned short*)(ws + 134217728);
    unsigned short* attnb = (unsigned short*)(ws + 167772160);

    const int M = BATCH * SEQ;  // 8192
    dim3 blk(256);

    hipLaunchKernelGGL(cast_bf16_kernel, dim3(NELEM / 8 / 256), blk, 0, stream,
                       x, xb, NELEM / 8);
    hipLaunchKernelGGL(cast_bf16_kernel, dim3(3 * EMBED * EMBED / 8 / 256), blk, 0, stream,
                       w_qkv, wqkvb, 3 * EMBED * EMBED / 8);
    hipLaunchKernelGGL(cast_bf16_kernel, dim3(EMBED * EMBED / 8 / 256), blk, 0, stream,
                       w_out, woutb, EMBED * EMBED / 8);

    // Q,K projection: A = x [8192,2048], B = Wqk rows 0..4095 -> grid (16,32)
    hipLaunchKernelGGL((gemm256_kernel<1>), dim3(16, 32), dim3(512), 0, stream,
                       xb, wqkvb, (float*)nullptr, qb, kb, M, 2 * EMBED, EMBED);

    // V^T projection: A = Wv [2048,2048], B = x [8192,2048] -> grid (32,8)
    hipLaunchKernelGGL((gemm256_kernel<2>), dim3(32, 8), dim3(512), 0, stream,
                       wqkvb + (size_t)2 * EMBED * EMBED, xb, (float*)nullptr,
                       vtb, (unsigned short*)nullptr, EMBED, M, EMBED);

    // attention
    hipLaunchKernelGGL(swa_mfma_kernel, dim3(BATCH * HEADS * (SEQ / 128)), dim3(512),
                       0, stream, qb, kb, vtb, attnb);

    // out projection: grid (8,32)
    hipLaunchKernelGGL((gemm256_kernel<0>), dim3(8, 32), dim3(512), 0, stream,
                       attnb, woutb, out, (unsigned short*)nullptr,
                       (unsigned short*)nullptr, M, EMBED, EMBED);
}